// Round 1
// baseline (34766.101 us; speedup 1.0000x reference)
//
#include <hip/hip_runtime.h>
#include <math.h>

#define B_ 256
#define T_ 128
#define D_ 64
#define H_ 512
#define A_ 128
#define O_ 32

__device__ __forceinline__ float sp_(float x) {
    // numerically stable softplus
    return fmaxf(x, 0.f) + log1pf(expf(-fabsf(x)));
}
__device__ __forceinline__ float sigm_(float x) {
    return 1.f / (1.f + expf(-x));
}

// ---------------- init: h = 0, leak = softplus(cm)+softplus(gleak) -----------
__global__ void init_kernel(float* __restrict__ h, float* __restrict__ leak,
                            const float* __restrict__ gleak,
                            const float* __restrict__ cm) {
    int i = blockIdx.x * 256 + threadIdx.x;
    if (i < B_ * H_) h[i] = 0.f;
    if (i < H_) leak[i] = sp_(cm[i]) + sp_(gleak[i]);
}

// ---------------- attention: Q = x_t@Wq+bq; scores vs cached K; ctx ----------
__global__ __launch_bounds__(256) void attn_kernel(
    const float* __restrict__ x, const float* __restrict__ Wq,
    const float* __restrict__ bq, const float* __restrict__ Khist,
    const float* __restrict__ Vhist, float* __restrict__ ctx, int t) {
    const int b = blockIdx.x;
    const int tid = threadIdx.x;
    __shared__ float xs[D_];
    __shared__ float q[A_];
    __shared__ float sc[T_];
    __shared__ float red[256];

    if (tid < D_) xs[tid] = x[(b * T_ + t) * D_ + tid];
    __syncthreads();
    if (tid < A_) {
        float acc = bq[tid];
        for (int d = 0; d < D_; ++d) acc += xs[d] * Wq[d * A_ + tid];
        q[tid] = acc;
    }
    __syncthreads();

    if (t == 0) {
        if (tid < A_) ctx[b * A_ + tid] = 0.f;
        return;
    }

    // scores: 32-lane group per history position s
    const float rscale = 0.08838834764831845f;  // 1/sqrt(128)
    int grp = tid >> 5;    // 0..7
    int lane = tid & 31;
    for (int s = grp; s < t; s += 8) {
        const float* Krow = Khist + (size_t)(b * T_ + s) * A_;
        float acc = 0.f;
        #pragma unroll
        for (int j = 0; j < 4; ++j) {
            int a = lane + 32 * j;
            acc += q[a] * Krow[a];
        }
        #pragma unroll
        for (int off = 16; off > 0; off >>= 1) acc += __shfl_xor(acc, off, 32);
        if (lane == 0) sc[s] = acc * rscale;
    }
    __syncthreads();

    // softmax over s in [0, t)
    float m = -1e30f;
    for (int s = tid; s < t; s += 256) m = fmaxf(m, sc[s]);
    red[tid] = m;
    __syncthreads();
    for (int off = 128; off > 0; off >>= 1) {
        if (tid < off) red[tid] = fmaxf(red[tid], red[tid + off]);
        __syncthreads();
    }
    m = red[0];
    __syncthreads();
    float ssum = 0.f;
    for (int s = tid; s < t; s += 256) {
        float e = expf(sc[s] - m);
        sc[s] = e;
        ssum += e;
    }
    red[tid] = ssum;
    __syncthreads();
    for (int off = 128; off > 0; off >>= 1) {
        if (tid < off) red[tid] += red[tid + off];
        __syncthreads();
    }
    float rs = 1.f / red[0];

    if (tid < A_) {
        float acc = 0.f;
        for (int s = 0; s < t; ++s)
            acc += sc[s] * Vhist[(size_t)(b * T_ + s) * A_ + tid];
        ctx[b * A_ + tid] = acc * rs;
    }
}

// ------------- base = x_t@W_gd[:64] + ctx@W_gd[576:] + b_gd  (B x 1024) ------
__global__ __launch_bounds__(256) void base_kernel(
    const float* __restrict__ x, const float* __restrict__ ctx,
    const float* __restrict__ W_gd, const float* __restrict__ b_gd,
    float* __restrict__ base, int t) {
    const int bg = blockIdx.x;           // 16 groups of 16 batch rows
    const int jg = blockIdx.y;           // 4 groups of 256 cols
    const int tid = threadIdx.x;
    const int j = jg * 256 + tid;
    const int b0 = bg * 16;
    __shared__ float xs[16][D_];
    __shared__ float cs[16][A_];
    for (int i = tid; i < 16 * D_; i += 256)
        xs[i / D_][i % D_] = x[((b0 + i / D_) * T_ + t) * D_ + (i % D_)];
    for (int i = tid; i < 16 * A_; i += 256)
        cs[i / A_][i % A_] = ctx[(b0 + i / A_) * A_ + (i % A_)];
    __syncthreads();

    float acc[16];
    float bj = b_gd[j];
    #pragma unroll
    for (int bb = 0; bb < 16; ++bb) acc[bb] = bj;
    for (int d = 0; d < D_; ++d) {
        float w = W_gd[d * 1024 + j];
        #pragma unroll
        for (int bb = 0; bb < 16; ++bb) acc[bb] += xs[bb][d] * w;
    }
    for (int a = 0; a < A_; ++a) {
        float w = W_gd[(D_ + H_ + a) * 1024 + j];
        #pragma unroll
        for (int bb = 0; bb < 16; ++bb) acc[bb] += cs[bb][a] * w;
    }
    #pragma unroll
    for (int bb = 0; bb < 16; ++bb) base[(b0 + bb) * 1024 + j] = acc[bb];
}

// ------------- RK4 stage: G = y@W_gd_h, Tau = y@W_tau, pointwise epilogue ----
template <int STAGE>
__global__ __launch_bounds__(256) void stage_kernel(
    const float* __restrict__ y, float* __restrict__ h,
    const float* __restrict__ base, const float* __restrict__ W_gd,
    const float* __restrict__ W_tau, const float* __restrict__ b_tau,
    const float* __restrict__ leak, const float* __restrict__ dts,
    float* __restrict__ k1, float* __restrict__ k2, float* __restrict__ k3,
    float* __restrict__ k4, float* __restrict__ ynext, int t) {
    __shared__ float Ys[32][33], Wg[32][33], Wd[32][33], Wt[32][33];
    const int c0 = blockIdx.x * 32;   // channel tile (0..511)
    const int b0 = blockIdx.y * 32;   // batch tile
    const int tid = threadIdx.x;
    const int tx = tid & 15, ty = tid >> 4;
    float ag[2][2] = {{0.f}}, ad[2][2] = {{0.f}}, at2[2][2] = {{0.f}};

    for (int k0 = 0; k0 < H_; k0 += 32) {
        for (int i = tid; i < 1024; i += 256) {
            int r = i >> 5, c = i & 31;
            Ys[r][c] = y[(b0 + r) * H_ + k0 + c];
            Wg[r][c] = W_gd[(size_t)(D_ + k0 + r) * 1024 + c0 + c];
            Wd[r][c] = W_gd[(size_t)(D_ + k0 + r) * 1024 + 512 + c0 + c];
            Wt[r][c] = W_tau[(size_t)(k0 + r) * H_ + c0 + c];
        }
        __syncthreads();
        #pragma unroll
        for (int kk = 0; kk < 32; ++kk) {
            float y0 = Ys[2 * ty][kk], y1 = Ys[2 * ty + 1][kk];
            float wg0 = Wg[kk][2 * tx], wg1 = Wg[kk][2 * tx + 1];
            float wd0 = Wd[kk][2 * tx], wd1 = Wd[kk][2 * tx + 1];
            float wt0 = Wt[kk][2 * tx], wt1 = Wt[kk][2 * tx + 1];
            ag[0][0] += y0 * wg0; ag[0][1] += y0 * wg1;
            ag[1][0] += y1 * wg0; ag[1][1] += y1 * wg1;
            ad[0][0] += y0 * wd0; ad[0][1] += y0 * wd1;
            ad[1][0] += y1 * wd0; ad[1][1] += y1 * wd1;
            at2[0][0] += y0 * wt0; at2[0][1] += y0 * wt1;
            at2[1][0] += y1 * wt0; at2[1][1] += y1 * wt1;
        }
        __syncthreads();
    }

    #pragma unroll
    for (int i = 0; i < 2; ++i) {
        int b = b0 + 2 * ty + i;
        float dt = dts[b * T_ + t];
        #pragma unroll
        for (int j = 0; j < 2; ++j) {
            int c = c0 + 2 * tx + j;
            int idx = b * H_ + c;
            float gate = ag[i][j] + base[b * 1024 + c];
            float dyn  = ad[i][j] + base[b * 1024 + 512 + c];
            float tau  = sp_(at2[i][j] + b_tau[c]);
            float yv = y[idx];
            float ki = (sigm_(gate) * tanhf(dyn) - yv) / (tau + leak[c] + 1e-6f);
            float hv = h[idx];
            if (STAGE == 1) {
                k1[idx] = ki;
                ynext[idx] = hv + dt * ki * (1.f / 3.f);
            } else if (STAGE == 2) {
                k2[idx] = ki;
                ynext[idx] = hv + dt * (ki - k1[idx] * (1.f / 3.f));
            } else if (STAGE == 3) {
                k3[idx] = ki;
                ynext[idx] = hv + dt * (k1[idx] - k2[idx] + ki);
            } else {
                h[idx] = hv + dt * (k1[idx] + 3.f * k2[idx] + 3.f * k3[idx] + ki) * 0.125f;
            }
        }
    }
}

// ------------- K/V projection of the freshly produced h_next ----------------
__global__ __launch_bounds__(256) void kv_kernel(
    const float* __restrict__ h, const float* __restrict__ Wk,
    const float* __restrict__ bk, const float* __restrict__ Wv,
    const float* __restrict__ bv, float* __restrict__ Khist,
    float* __restrict__ Vhist, int t) {
    const int b = blockIdx.x;
    const int tid = threadIdx.x;
    __shared__ float hs[H_];
    for (int i = tid; i < H_; i += 256) hs[i] = h[b * H_ + i];
    __syncthreads();
    const int a = tid & 127;
    const float* W = (tid < 128) ? Wk : Wv;
    float acc = (tid < 128) ? bk[a] : bv[a];
    for (int k = 0; k < H_; ++k) acc += hs[k] * W[k * A_ + a];
    if (tid < 128)
        Khist[(size_t)(b * T_ + t) * A_ + a] = acc;
    else
        Vhist[(size_t)(b * T_ + t) * A_ + a] = acc;
}

// ------------- final fc: out = h @ W_fc + b_fc ------------------------------
__global__ void fc_kernel(const float* __restrict__ h,
                          const float* __restrict__ W_fc,
                          const float* __restrict__ b_fc,
                          float* __restrict__ out) {
    const int b = blockIdx.x;
    const int o = threadIdx.x;
    if (o >= O_) return;
    float acc = b_fc[o];
    for (int k = 0; k < H_; ++k) acc += h[b * H_ + k] * W_fc[k * O_ + o];
    out[b * O_ + o] = acc;
}

extern "C" void kernel_launch(void* const* d_in, const int* in_sizes, int n_in,
                              void* d_out, int out_size, void* d_ws,
                              size_t ws_size, hipStream_t stream) {
    (void)in_sizes; (void)n_in; (void)out_size; (void)ws_size;
    const float* x     = (const float*)d_in[0];   // B,T,D
    const float* dts   = (const float*)d_in[1];   // B,T
    const float* Wq    = (const float*)d_in[2];   // D,A
    const float* bq    = (const float*)d_in[3];   // A
    const float* Wk    = (const float*)d_in[4];   // H,A
    const float* bk    = (const float*)d_in[5];   // A
    const float* Wv    = (const float*)d_in[6];   // H,A
    const float* bv    = (const float*)d_in[7];   // A
    const float* W_gd  = (const float*)d_in[8];   // 704,1024
    const float* b_gd  = (const float*)d_in[9];   // 1024
    const float* W_tau = (const float*)d_in[10];  // H,H
    const float* b_tau = (const float*)d_in[11];  // H
    const float* gleak = (const float*)d_in[12];  // H
    const float* cm    = (const float*)d_in[13];  // H
    const float* W_fc  = (const float*)d_in[14];  // H,O
    const float* b_fc  = (const float*)d_in[15];  // O
    float* out = (float*)d_out;

    float* ws   = (float*)d_ws;
    float* h    = ws;                    // B*H
    float* ya   = h + B_ * H_;           // B*H
    float* yb   = ya + B_ * H_;          // B*H
    float* k1   = yb + B_ * H_;          // B*H
    float* k2   = k1 + B_ * H_;
    float* k3   = k2 + B_ * H_;
    float* k4   = k3 + B_ * H_;
    float* base = k4 + B_ * H_;          // B*1024
    float* ctx  = base + B_ * 1024;      // B*A
    float* leak = ctx + B_ * A_;         // H
    float* Khist = leak + H_;            // B*T*A
    float* Vhist = Khist + (size_t)B_ * T_ * A_;

    init_kernel<<<512, 256, 0, stream>>>(h, leak, gleak, cm);

    for (int t = 0; t < T_; ++t) {
        attn_kernel<<<B_, 256, 0, stream>>>(x, Wq, bq, Khist, Vhist, ctx, t);
        base_kernel<<<dim3(16, 4), 256, 0, stream>>>(x, ctx, W_gd, b_gd, base, t);
        stage_kernel<1><<<dim3(16, 8), 256, 0, stream>>>(
            h, h, base, W_gd, W_tau, b_tau, leak, dts, k1, k2, k3, k4, ya, t);
        stage_kernel<2><<<dim3(16, 8), 256, 0, stream>>>(
            ya, h, base, W_gd, W_tau, b_tau, leak, dts, k1, k2, k3, k4, yb, t);
        stage_kernel<3><<<dim3(16, 8), 256, 0, stream>>>(
            yb, h, base, W_gd, W_tau, b_tau, leak, dts, k1, k2, k3, k4, ya, t);
        stage_kernel<4><<<dim3(16, 8), 256, 0, stream>>>(
            ya, h, base, W_gd, W_tau, b_tau, leak, dts, k1, k2, k3, k4, h, t);
        kv_kernel<<<B_, 256, 0, stream>>>(h, Wk, bk, Wv, bv, Khist, Vhist, t);
    }
    fc_kernel<<<B_, 64, 0, stream>>>(h, W_fc, b_fc, out);
}

// Round 2
// 13000.079 us; speedup vs baseline: 2.6743x; 2.6743x over previous
//
#include <hip/hip_runtime.h>
#include <math.h>

#define B_ 256
#define T_ 128
#define D_ 64
#define H_ 512
#define A_ 128
#define O_ 32

typedef __attribute__((ext_vector_type(8))) short short8;
typedef __attribute__((ext_vector_type(4))) float floatx4;

__device__ __forceinline__ float sp_(float x) {
    // numerically stable softplus
    return fmaxf(x, 0.f) + log1pf(expf(-fabsf(x)));
}
__device__ __forceinline__ float sigm_(float x) {
    return 1.f / (1.f + expf(-x));
}
__device__ __forceinline__ unsigned short f2bf_(float f) {
    unsigned int u = __float_as_uint(f);
    return (unsigned short)((u + 0x7FFFu + ((u >> 16) & 1u)) >> 16);
}

// ---------------- init: h = 0 (fp32 + packed bf16), leak --------------------
__global__ void init_kernel(float* __restrict__ h,
                            unsigned short* __restrict__ hpack,
                            float* __restrict__ leak,
                            const float* __restrict__ gleak,
                            const float* __restrict__ cm) {
    int i = blockIdx.x * 256 + threadIdx.x;
    if (i < B_ * H_) {
        h[i] = 0.f;
        hpack[i] = 0;
    }
    if (i < H_) leak[i] = sp_(cm[i]) + sp_(gleak[i]);
}

// -------- pack [Wg | Wd | Wtau] (K=512, N=512 each) into MFMA B-frag order --
// frag id = (ct*16 + kb)*3 + s ; within frag: lane l holds B[k=kb*32+(l>>4)*8+j][n=l&15]
__global__ void pack_w_kernel(const float* __restrict__ W_gd,
                              const float* __restrict__ W_tau,
                              unsigned short* __restrict__ Wpack) {
    int gid = blockIdx.x * 256 + threadIdx.x;  // 0 .. 786431
    int j = gid & 7;
    int l = (gid >> 3) & 63;
    int frag = gid >> 9;
    int s = frag % 3;
    int rem = frag / 3;
    int kb = rem & 15;
    int ct = rem >> 4;
    int k = kb * 32 + (l >> 4) * 8 + j;
    int c = ct * 16 + (l & 15);
    float v;
    if (s == 0)      v = W_gd[(size_t)(D_ + k) * 1024 + c];
    else if (s == 1) v = W_gd[(size_t)(D_ + k) * 1024 + 512 + c];
    else             v = W_tau[(size_t)k * 512 + c];
    Wpack[gid] = f2bf_(v);
}

// ---------------- attention: Q = x_t@Wq+bq; scores vs cached K; ctx ----------
__global__ __launch_bounds__(256) void attn_kernel(
    const float* __restrict__ x, const float* __restrict__ Wq,
    const float* __restrict__ bq, const float* __restrict__ Khist,
    const float* __restrict__ Vhist, float* __restrict__ ctx, int t) {
    const int b = blockIdx.x;
    const int tid = threadIdx.x;
    __shared__ float xs[D_];
    __shared__ float q[A_];
    __shared__ float sc[T_];
    __shared__ float red[256];

    if (tid < D_) xs[tid] = x[(b * T_ + t) * D_ + tid];
    __syncthreads();
    if (tid < A_) {
        float acc = bq[tid];
        for (int d = 0; d < D_; ++d) acc += xs[d] * Wq[d * A_ + tid];
        q[tid] = acc;
    }
    __syncthreads();

    if (t == 0) {
        if (tid < A_) ctx[b * A_ + tid] = 0.f;
        return;
    }

    const float rscale = 0.08838834764831845f;  // 1/sqrt(128)
    int grp = tid >> 5;
    int lane = tid & 31;
    for (int s = grp; s < t; s += 8) {
        const float* Krow = Khist + (size_t)(b * T_ + s) * A_;
        float acc = 0.f;
        #pragma unroll
        for (int j = 0; j < 4; ++j) {
            int a = lane + 32 * j;
            acc += q[a] * Krow[a];
        }
        #pragma unroll
        for (int off = 16; off > 0; off >>= 1) acc += __shfl_xor(acc, off, 32);
        if (lane == 0) sc[s] = acc * rscale;
    }
    __syncthreads();

    float m = -1e30f;
    for (int s = tid; s < t; s += 256) m = fmaxf(m, sc[s]);
    red[tid] = m;
    __syncthreads();
    for (int off = 128; off > 0; off >>= 1) {
        if (tid < off) red[tid] = fmaxf(red[tid], red[tid + off]);
        __syncthreads();
    }
    m = red[0];
    __syncthreads();
    float ssum = 0.f;
    for (int s = tid; s < t; s += 256) {
        float e = expf(sc[s] - m);
        sc[s] = e;
        ssum += e;
    }
    red[tid] = ssum;
    __syncthreads();
    for (int off = 128; off > 0; off >>= 1) {
        if (tid < off) red[tid] += red[tid + off];
        __syncthreads();
    }
    float rs = 1.f / red[0];

    if (tid < A_) {
        float acc = 0.f;
        for (int s = 0; s < t; ++s)
            acc += sc[s] * Vhist[(size_t)(b * T_ + s) * A_ + tid];
        ctx[b * A_ + tid] = acc * rs;
    }
}

// ------------- base = x_t@W_gd[:64] + ctx@W_gd[576:] + b_gd  (B x 1024) ------
__global__ __launch_bounds__(256) void base_kernel(
    const float* __restrict__ x, const float* __restrict__ ctx,
    const float* __restrict__ W_gd, const float* __restrict__ b_gd,
    float* __restrict__ base, int t) {
    const int bg = blockIdx.x;
    const int jg = blockIdx.y;
    const int tid = threadIdx.x;
    const int j = jg * 256 + tid;
    const int b0 = bg * 16;
    __shared__ float xs[16][D_];
    __shared__ float cs[16][A_];
    for (int i = tid; i < 16 * D_; i += 256)
        xs[i / D_][i % D_] = x[((b0 + i / D_) * T_ + t) * D_ + (i % D_)];
    for (int i = tid; i < 16 * A_; i += 256)
        cs[i / A_][i % A_] = ctx[(b0 + i / A_) * A_ + (i % A_)];
    __syncthreads();

    float acc[16];
    float bj = b_gd[j];
    #pragma unroll
    for (int bb = 0; bb < 16; ++bb) acc[bb] = bj;
    for (int d = 0; d < D_; ++d) {
        float w = W_gd[d * 1024 + j];
        #pragma unroll
        for (int bb = 0; bb < 16; ++bb) acc[bb] += xs[bb][d] * w;
    }
    for (int a = 0; a < A_; ++a) {
        float w = W_gd[(D_ + H_ + a) * 1024 + j];
        #pragma unroll
        for (int bb = 0; bb < 16; ++bb) acc[bb] += cs[bb][a] * w;
    }
    #pragma unroll
    for (int bb = 0; bb < 16; ++bb) base[(b0 + bb) * 1024 + j] = acc[bb];
}

// ------------- RK4 stage via MFMA: [gate|dyn|tau] = y @ [Wg|Wd|Wt] ----------
// One wave = 16 batch rows x 16 channels, 3 MFMA chains, epilogue in-register.
// No LDS, no barriers. A (y) pre-packed bf16; B (weights) pre-packed bf16.
template <int STAGE>
__global__ __launch_bounds__(128) void stage_mfma_kernel(
    const unsigned short* __restrict__ ypack, const float* __restrict__ y,
    const float* __restrict__ h, const float* __restrict__ base,
    const unsigned short* __restrict__ Wpack, const float* __restrict__ b_tau,
    const float* __restrict__ leak, const float* __restrict__ dts,
    float* __restrict__ k1, float* __restrict__ k2, float* __restrict__ k3,
    float* __restrict__ ynext, unsigned short* __restrict__ ynext_pack, int t) {
    const int tid = threadIdx.x;
    const int lane = tid & 63;
    const int w = blockIdx.x * 2 + (tid >> 6);  // 0..511
    const int m_tile = w >> 5;                  // 0..15 (16 batch rows each)
    const int ct = w & 31;                      // 0..31 (16 channels each)

    floatx4 accg = {0.f, 0.f, 0.f, 0.f};
    floatx4 accd = {0.f, 0.f, 0.f, 0.f};
    floatx4 acct = {0.f, 0.f, 0.f, 0.f};

    const short8* Ap = (const short8*)ypack;
    const short8* Wp = (const short8*)Wpack;
    #pragma unroll
    for (int kb = 0; kb < 16; ++kb) {
        short8 a  = Ap[(m_tile * 16 + kb) * 64 + lane];
        short8 bg = Wp[((ct * 16 + kb) * 3 + 0) * 64 + lane];
        short8 bd = Wp[((ct * 16 + kb) * 3 + 1) * 64 + lane];
        short8 bt = Wp[((ct * 16 + kb) * 3 + 2) * 64 + lane];
        accg = __builtin_amdgcn_mfma_f32_16x16x32_bf16(a, bg, accg, 0, 0, 0);
        accd = __builtin_amdgcn_mfma_f32_16x16x32_bf16(a, bd, accd, 0, 0, 0);
        acct = __builtin_amdgcn_mfma_f32_16x16x32_bf16(a, bt, acct, 0, 0, 0);
    }

    const int quad = lane >> 4;
    const int col = lane & 15;
    const int c = ct * 16 + col;
    const float btau = b_tau[c];
    const float lk = leak[c] + 1e-6f;
    const int lane_p = ((c >> 3) & 3) * 16;           // + (b&15) below
    const int pbase = (m_tile * 16 + (c >> 5)) * 512 + (c & 7);

    #pragma unroll
    for (int i = 0; i < 4; ++i) {
        const int b = m_tile * 16 + quad * 4 + i;
        const int idx = b * H_ + c;
        const float dt = dts[b * T_ + t];
        float gate = accg[i] + base[b * 1024 + c];
        float dyn  = accd[i] + base[b * 1024 + 512 + c];
        float tau  = sp_(acct[i] + btau);
        float yv = y[idx];
        float ki = (sigm_(gate) * tanhf(dyn) - yv) / (tau + lk);
        float hv = h[idx];
        float yn;
        if (STAGE == 1) {
            k1[idx] = ki;
            yn = hv + dt * ki * (1.f / 3.f);
        } else if (STAGE == 2) {
            k2[idx] = ki;
            yn = hv + dt * (ki - k1[idx] * (1.f / 3.f));
        } else if (STAGE == 3) {
            k3[idx] = ki;
            yn = hv + dt * (k1[idx] - k2[idx] + ki);
        } else {
            yn = hv + dt * (k1[idx] + 3.f * k2[idx] + 3.f * k3[idx] + ki) * 0.125f;
        }
        ynext[idx] = yn;
        ynext_pack[pbase + (lane_p + (b & 15)) * 8] = f2bf_(yn);
    }
}

// ------------- K/V projection of the freshly produced h_next ----------------
__global__ __launch_bounds__(256) void kv_kernel(
    const float* __restrict__ h, const float* __restrict__ Wk,
    const float* __restrict__ bk, const float* __restrict__ Wv,
    const float* __restrict__ bv, float* __restrict__ Khist,
    float* __restrict__ Vhist, int t) {
    const int b = blockIdx.x;
    const int tid = threadIdx.x;
    __shared__ float hs[H_];
    for (int i = tid; i < H_; i += 256) hs[i] = h[b * H_ + i];
    __syncthreads();
    const int a = tid & 127;
    const float* W = (tid < 128) ? Wk : Wv;
    float acc = (tid < 128) ? bk[a] : bv[a];
    for (int k = 0; k < H_; ++k) acc += hs[k] * W[k * A_ + a];
    if (tid < 128)
        Khist[(size_t)(b * T_ + t) * A_ + a] = acc;
    else
        Vhist[(size_t)(b * T_ + t) * A_ + a] = acc;
}

// ------------- final fc: out = h @ W_fc + b_fc ------------------------------
__global__ void fc_kernel(const float* __restrict__ h,
                          const float* __restrict__ W_fc,
                          const float* __restrict__ b_fc,
                          float* __restrict__ out) {
    const int b = blockIdx.x;
    const int o = threadIdx.x;
    if (o >= O_) return;
    float acc = b_fc[o];
    for (int k = 0; k < H_; ++k) acc += h[b * H_ + k] * W_fc[k * O_ + o];
    out[b * O_ + o] = acc;
}

extern "C" void kernel_launch(void* const* d_in, const int* in_sizes, int n_in,
                              void* d_out, int out_size, void* d_ws,
                              size_t ws_size, hipStream_t stream) {
    (void)in_sizes; (void)n_in; (void)out_size; (void)ws_size;
    const float* x     = (const float*)d_in[0];   // B,T,D
    const float* dts   = (const float*)d_in[1];   // B,T
    const float* Wq    = (const float*)d_in[2];   // D,A
    const float* bq    = (const float*)d_in[3];   // A
    const float* Wk    = (const float*)d_in[4];   // H,A
    const float* bk    = (const float*)d_in[5];   // A
    const float* Wv    = (const float*)d_in[6];   // H,A
    const float* bv    = (const float*)d_in[7];   // A
    const float* W_gd  = (const float*)d_in[8];   // 704,1024
    const float* b_gd  = (const float*)d_in[9];   // 1024
    const float* W_tau = (const float*)d_in[10];  // H,H
    const float* b_tau = (const float*)d_in[11];  // H
    const float* gleak = (const float*)d_in[12];  // H
    const float* cm    = (const float*)d_in[13];  // H
    const float* W_fc  = (const float*)d_in[14];  // H,O
    const float* b_fc  = (const float*)d_in[15];  // O
    float* out = (float*)d_out;

    float* ws   = (float*)d_ws;
    float* h    = ws;                        // B*H
    float* ya   = h + B_ * H_;               // B*H
    float* yb   = ya + B_ * H_;              // B*H
    float* k1   = yb + B_ * H_;              // B*H
    float* k2   = k1 + B_ * H_;
    float* k3   = k2 + B_ * H_;
    float* base = k3 + B_ * H_;              // B*1024
    float* ctx  = base + B_ * 1024;          // B*A
    float* leak = ctx + B_ * A_;             // H
    float* Khist = leak + H_;                // B*T*A
    float* Vhist = Khist + (size_t)B_ * T_ * A_;
    unsigned short* Wpack  = (unsigned short*)(Vhist + (size_t)B_ * T_ * A_);
    unsigned short* hpack  = Wpack + 32 * 16 * 3 * 512;   // 786432 ushorts
    unsigned short* yapack = hpack + B_ * H_;
    unsigned short* ybpack = yapack + B_ * H_;

    init_kernel<<<512, 256, 0, stream>>>(h, hpack, leak, gleak, cm);
    pack_w_kernel<<<3072, 256, 0, stream>>>(W_gd, W_tau, Wpack);

    for (int t = 0; t < T_; ++t) {
        attn_kernel<<<B_, 256, 0, stream>>>(x, Wq, bq, Khist, Vhist, ctx, t);
        base_kernel<<<dim3(16, 4), 256, 0, stream>>>(x, ctx, W_gd, b_gd, base, t);
        stage_mfma_kernel<1><<<256, 128, 0, stream>>>(
            hpack, h, h, base, Wpack, b_tau, leak, dts, k1, k2, k3, ya, yapack, t);
        stage_mfma_kernel<2><<<256, 128, 0, stream>>>(
            yapack, ya, h, base, Wpack, b_tau, leak, dts, k1, k2, k3, yb, ybpack, t);
        stage_mfma_kernel<3><<<256, 128, 0, stream>>>(
            ybpack, yb, h, base, Wpack, b_tau, leak, dts, k1, k2, k3, ya, yapack, t);
        stage_mfma_kernel<4><<<256, 128, 0, stream>>>(
            yapack, ya, h, base, Wpack, b_tau, leak, dts, k1, k2, k3, h, hpack, t);
        kv_kernel<<<B_, 256, 0, stream>>>(h, Wk, bk, Wv, bv, Khist, Vhist, t);
    }
    fc_kernel<<<B_, 64, 0, stream>>>(h, W_fc, b_fc, out);
}

// Round 4
// 12211.044 us; speedup vs baseline: 2.8471x; 1.0646x over previous
//
#include <hip/hip_runtime.h>
#include <math.h>

#define B_ 256
#define T_ 128
#define D_ 64
#define H_ 512
#define A_ 128
#define O_ 32

typedef __attribute__((ext_vector_type(8))) short short8;
typedef __attribute__((ext_vector_type(4))) float floatx4;

__device__ __forceinline__ float sp_(float x) {
    return fmaxf(x, 0.f) + log1pf(expf(-fabsf(x)));
}
__device__ __forceinline__ float sigm_(float x) {
    return 1.f / (1.f + expf(-x));
}
__device__ __forceinline__ unsigned short f2bf_(float f) {
    unsigned int u = __float_as_uint(f);
    return (unsigned short)((u + 0x7FFFu + ((u >> 16) & 1u)) >> 16);
}

// ---------------- init: hpack = 0, barriers = 0 -----------------------------
__global__ void init_kernel(unsigned short* __restrict__ hpack,
                            unsigned* __restrict__ bar) {
    int i = blockIdx.x * 256 + threadIdx.x;
    if (i < B_ * H_) hpack[i] = 0;
    if (i < 512) bar[i] = 0u;
}

// -------- pack all weights into MFMA B-frag bf16 order ----------------------
// regions (ushort offsets): y:[0,786432) x:[786432,851968) c:[851968,983040)
//                           kv:[983040,1114112)
__global__ void pack_w_kernel(const float* __restrict__ W_gd,
                              const float* __restrict__ W_tau,
                              const float* __restrict__ Wk,
                              const float* __restrict__ Wv,
                              unsigned short* __restrict__ Wpack) {
    int gid = blockIdx.x * 256 + threadIdx.x;
    if (gid >= 1114112) return;
    int j = gid & 7;
    int l = (gid >> 3) & 63;
    int kpart = (l >> 4) * 8 + j;
    int npart = l & 15;
    float v;
    if (gid < 786432) {
        int f = gid >> 9;
        int s = f % 3;
        int rem = f / 3;
        int kb = rem & 15, ct = rem >> 4;
        int k = kb * 32 + kpart;
        int c = ct * 16 + npart;
        if (s == 0)      v = W_gd[(size_t)(D_ + k) * 1024 + c];
        else if (s == 1) v = W_gd[(size_t)(D_ + k) * 1024 + 512 + c];
        else             v = W_tau[(size_t)k * 512 + c];
    } else if (gid < 851968) {
        int r = gid - 786432;
        int f = r >> 9;
        int s = f & 1, kb = (f >> 1) & 1, ct = f >> 2;
        int k = kb * 32 + kpart;
        int c = ct * 16 + npart;
        v = W_gd[(size_t)k * 1024 + s * 512 + c];
    } else if (gid < 983040) {
        int r = gid - 851968;
        int f = r >> 9;
        int s = f & 1, kb = (f >> 1) & 3, ct = f >> 3;
        int k = kb * 32 + kpart;
        int c = ct * 16 + npart;
        v = W_gd[(size_t)(D_ + H_ + k) * 1024 + s * 512 + c];
    } else {
        int r = gid - 983040;
        int f = r >> 9;
        int kb = f & 15, c4 = f >> 4;
        int k = kb * 32 + kpart;
        int n = (c4 & 7) * 16 + npart;
        v = (c4 < 8) ? Wk[(size_t)k * A_ + n] : Wv[(size_t)k * A_ + n];
    }
    Wpack[gid] = f2bf_(v);
}

// ---------------- group barrier: 16 blocks, generation counter --------------
__device__ __forceinline__ void gsync16(unsigned* barg) {
    __syncthreads();
    if (threadIdx.x == 0) {
        unsigned g = __hip_atomic_load(barg + 1, __ATOMIC_RELAXED,
                                       __HIP_MEMORY_SCOPE_AGENT);
        unsigned old = __hip_atomic_fetch_add(barg, 1u, __ATOMIC_ACQ_REL,
                                              __HIP_MEMORY_SCOPE_AGENT);
        if (old == 15u) {
            __hip_atomic_store(barg, 0u, __ATOMIC_RELAXED,
                               __HIP_MEMORY_SCOPE_AGENT);
            __hip_atomic_fetch_add(barg + 1, 1u, __ATOMIC_ACQ_REL,
                                   __HIP_MEMORY_SCOPE_AGENT);
        } else {
            while (__hip_atomic_load(barg + 1, __ATOMIC_RELAXED,
                                     __HIP_MEMORY_SCOPE_AGENT) == g) {
                __builtin_amdgcn_s_sleep(1);
            }
        }
    }
    __syncthreads();
    __builtin_amdgcn_fence(__ATOMIC_ACQUIRE, "agent");
}

struct P {
    const float *x, *dts, *Wq, *bq, *bk, *bv, *b_gd, *b_tau, *gleak, *cm,
        *W_fc, *b_fc;
    float *h, *ctx, *Khist, *Vhist, *out;
    const unsigned short *Wy, *Wx, *Wc, *Wkv;
    unsigned short *hpack, *yapack, *ybpack;
    unsigned* bar;
};

__device__ __forceinline__ void gemm3(const short8 (&wg)[16],
                                      const short8 (&wd)[16],
                                      const short8 (&wt)[16],
                                      const short8* Ap, int m_tile, int lane,
                                      floatx4& ag, floatx4& ad, floatx4& at) {
    #pragma unroll
    for (int kb = 0; kb < 16; ++kb) {
        short8 a = Ap[(m_tile * 16 + kb) * 64 + lane];
        ag = __builtin_amdgcn_mfma_f32_16x16x32_bf16(a, wg[kb], ag, 0, 0, 0);
        ad = __builtin_amdgcn_mfma_f32_16x16x32_bf16(a, wd[kb], ad, 0, 0, 0);
        at = __builtin_amdgcn_mfma_f32_16x16x32_bf16(a, wt[kb], at, 0, 0, 0);
    }
}

__global__ __launch_bounds__(128, 1) void fused_kernel(P p) {
    const int tid = threadIdx.x;
    const int bid = blockIdx.x;
    const int lane = tid & 63;
    // group decomposition: group g = 16 blocks (XCD-local under %8 round-robin)
    const int g = ((bid & 7) << 1) | ((bid >> 3) & 1);
    const int l = bid >> 4;
    const int w_local = l * 2 + (tid >> 6);  // 0..31 within group
    const int ct = w_local;                  // channel strip 0..31
    const int m_tile = g;                    // batch tile = group
    unsigned* barg = p.bar + g * 32;

    __shared__ float WqL[D_ * 129];
    __shared__ float xs[D_];
    __shared__ float q[A_];
    __shared__ float sc[T_];
    __shared__ float red2[2];

    // persistent y-part B-fragments (192 VGPRs)
    short8 wg[16], wd[16], wt[16];
    {
        const short8* Wy8 = (const short8*)p.Wy;
        #pragma unroll
        for (int kb = 0; kb < 16; ++kb) {
            wg[kb] = Wy8[((ct * 16 + kb) * 3 + 0) * 64 + lane];
            wd[kb] = Wy8[((ct * 16 + kb) * 3 + 1) * 64 + lane];
            wt[kb] = Wy8[((ct * 16 + kb) * 3 + 2) * 64 + lane];
        }
    }
    const int quad = lane >> 4;
    const int c = ct * 16 + (lane & 15);
    const float btau = p.b_tau[c];
    const float lk = sp_(p.cm[c]) + sp_(p.gleak[c]) + 1e-6f;
    const float bgd_g = p.b_gd[c];
    const float bgd_d = p.b_gd[512 + c];
    const int lane_p = ((c >> 3) & 3) * 16;
    const int pbase = (m_tile * 16 + (c >> 5)) * 512 + (c & 7);
    const int r = g * 16 + l;  // attention/fc row for this block

    // kv constants (only waves w_local < 16 active in phase F)
    const int c4 = w_local;
    const int a_col = (c4 & 7) * 16 + (lane & 15);
    float kv_bias = 0.f;
    float* kv_dst = p.Khist;
    if (w_local < 16) {
        kv_bias = (c4 < 8 ? p.bk : p.bv)[a_col];
        kv_dst = (c4 < 8) ? p.Khist : p.Vhist;
    }

    // Wq -> LDS (stride 129 to break bank alignment)
    for (int i = tid; i < D_ * A_; i += 128) {
        int d = i >> 7, a = i & 127;
        WqL[d * 129 + a] = p.Wq[i];
    }

    floatx4 hreg = {0.f, 0.f, 0.f, 0.f};
    floatx4 rk1, rk2, rk3, baseg, based, ycur, dt4;

    const short8* Wx8 = (const short8*)p.Wx;
    const short8* Wc8 = (const short8*)p.Wc;
    const short8* Wkv8 = (const short8*)p.Wkv;
    const short8* Ahp = (const short8*)p.hpack;
    const short8* Aya = (const short8*)p.yapack;
    const short8* Ayb = (const short8*)p.ybpack;

    __syncthreads();  // WqL ready

    for (int t = 0; t < T_; ++t) {
        // ---------- phase A: attention for row r ----------
        {
            if (tid < 16)
                ((float4*)xs)[tid] = ((const float4*)&p.x[(r * T_ + t) * D_])[tid];
            __syncthreads();
            float qa = p.bq[tid];
            #pragma unroll 8
            for (int d = 0; d < D_; ++d) qa += xs[d] * WqL[d * 129 + tid];
            q[tid] = qa;
            __syncthreads();
            if (t == 0) {
                p.ctx[r * A_ + tid] = 0.f;
            } else {
                const float rscale = 0.08838834764831845f;  // 1/sqrt(128)
                const int grp = tid >> 4, ln = tid & 15;
                for (int s = grp; s < t; s += 8) {
                    const float4* Kr =
                        (const float4*)(p.Khist + (size_t)(r * T_ + s) * A_);
                    float4 k0 = Kr[ln * 2], k1v = Kr[ln * 2 + 1];
                    float a2 = k0.x * q[ln * 8 + 0] + k0.y * q[ln * 8 + 1] +
                               k0.z * q[ln * 8 + 2] + k0.w * q[ln * 8 + 3] +
                               k1v.x * q[ln * 8 + 4] + k1v.y * q[ln * 8 + 5] +
                               k1v.z * q[ln * 8 + 6] + k1v.w * q[ln * 8 + 7];
                    #pragma unroll
                    for (int off = 8; off > 0; off >>= 1)
                        a2 += __shfl_xor(a2, off, 16);
                    if (ln == 0) sc[s] = a2 * rscale;
                }
                __syncthreads();
                float mloc = -1e30f;
                for (int s = tid; s < t; s += 128) mloc = fmaxf(mloc, sc[s]);
                #pragma unroll
                for (int off = 32; off > 0; off >>= 1)
                    mloc = fmaxf(mloc, __shfl_xor(mloc, off, 64));
                if (lane == 0) red2[tid >> 6] = mloc;
                __syncthreads();
                float m = fmaxf(red2[0], red2[1]);
                float ssum = 0.f;
                for (int s = tid; s < t; s += 128) {
                    float e = expf(sc[s] - m);
                    sc[s] = e;
                    ssum += e;
                }
                #pragma unroll
                for (int off = 32; off > 0; off >>= 1)
                    ssum += __shfl_xor(ssum, off, 64);
                __syncthreads();  // all reads of red2(max) and writes of sc done
                if (lane == 0) red2[tid >> 6] = ssum;
                __syncthreads();
                float rs = 1.f / (red2[0] + red2[1]);
                float ca = 0.f;
                #pragma unroll 4
                for (int s = 0; s < t; ++s)
                    ca += sc[s] * p.Vhist[(size_t)(r * T_ + s) * A_ + tid];
                p.ctx[r * A_ + tid] = ca * rs;
            }
        }
        gsync16(barg);

        // ---------- phase B: stage1 + base fold (x/ctx MFMA) ----------
        {
            const int mrow = lane & 15;
            const int kq = lane >> 4;
            #pragma unroll
            for (int i = 0; i < 4; ++i)
                dt4[i] = p.dts[(m_tile * 16 + quad * 4 + i) * T_ + t];

            const float4* xrow =
                (const float4*)&p.x[((m_tile * 16 + mrow) * T_ + t) * D_];
            const float4* crow =
                (const float4*)&p.ctx[(m_tile * 16 + mrow) * A_];
            floatx4 bg = {0.f, 0.f, 0.f, 0.f};
            floatx4 bd = {0.f, 0.f, 0.f, 0.f};
            #pragma unroll
            for (int kb = 0; kb < 2; ++kb) {
                float4 u = xrow[kb * 8 + kq * 2], v = xrow[kb * 8 + kq * 2 + 1];
                short8 ax;
                ax[0] = (short)f2bf_(u.x); ax[1] = (short)f2bf_(u.y);
                ax[2] = (short)f2bf_(u.z); ax[3] = (short)f2bf_(u.w);
                ax[4] = (short)f2bf_(v.x); ax[5] = (short)f2bf_(v.y);
                ax[6] = (short)f2bf_(v.z); ax[7] = (short)f2bf_(v.w);
                bg = __builtin_amdgcn_mfma_f32_16x16x32_bf16(
                    ax, Wx8[((ct * 2 + kb) * 2 + 0) * 64 + lane], bg, 0, 0, 0);
                bd = __builtin_amdgcn_mfma_f32_16x16x32_bf16(
                    ax, Wx8[((ct * 2 + kb) * 2 + 1) * 64 + lane], bd, 0, 0, 0);
            }
            #pragma unroll
            for (int kb = 0; kb < 4; ++kb) {
                float4 u = crow[kb * 8 + kq * 2], v = crow[kb * 8 + kq * 2 + 1];
                short8 ac;
                ac[0] = (short)f2bf_(u.x); ac[1] = (short)f2bf_(u.y);
                ac[2] = (short)f2bf_(u.z); ac[3] = (short)f2bf_(u.w);
                ac[4] = (short)f2bf_(v.x); ac[5] = (short)f2bf_(v.y);
                ac[6] = (short)f2bf_(v.z); ac[7] = (short)f2bf_(v.w);
                bg = __builtin_amdgcn_mfma_f32_16x16x32_bf16(
                    ac, Wc8[((ct * 4 + kb) * 2 + 0) * 64 + lane], bg, 0, 0, 0);
                bd = __builtin_amdgcn_mfma_f32_16x16x32_bf16(
                    ac, Wc8[((ct * 4 + kb) * 2 + 1) * 64 + lane], bd, 0, 0, 0);
            }
            floatx4 ag = {0.f, 0.f, 0.f, 0.f};
            floatx4 ad = {0.f, 0.f, 0.f, 0.f};
            floatx4 at = {0.f, 0.f, 0.f, 0.f};
            gemm3(wg, wd, wt, Ahp, m_tile, lane, ag, ad, at);
            #pragma unroll
            for (int i = 0; i < 4; ++i) {
                baseg[i] = bg[i] + bgd_g;
                based[i] = bd[i] + bgd_d;
                float gate = ag[i] + baseg[i];
                float dyn = ad[i] + based[i];
                float tau = sp_(at[i] + btau);
                float ki = (sigm_(gate) * tanhf(dyn) - hreg[i]) / (tau + lk);
                rk1[i] = ki;
                float yn = hreg[i] + dt4[i] * ki * (1.f / 3.f);
                ycur[i] = yn;
                p.yapack[pbase + (lane_p + (quad * 4 + i)) * 8] = f2bf_(yn);
            }
        }
        gsync16(barg);

        // ---------- stage 2 ----------
        {
            floatx4 ag = {0.f, 0.f, 0.f, 0.f};
            floatx4 ad = {0.f, 0.f, 0.f, 0.f};
            floatx4 at = {0.f, 0.f, 0.f, 0.f};
            gemm3(wg, wd, wt, Aya, m_tile, lane, ag, ad, at);
            #pragma unroll
            for (int i = 0; i < 4; ++i) {
                float gate = ag[i] + baseg[i];
                float dyn = ad[i] + based[i];
                float tau = sp_(at[i] + btau);
                float ki = (sigm_(gate) * tanhf(dyn) - ycur[i]) / (tau + lk);
                rk2[i] = ki;
                float yn = hreg[i] + dt4[i] * (ki - rk1[i] * (1.f / 3.f));
                ycur[i] = yn;
                p.ybpack[pbase + (lane_p + (quad * 4 + i)) * 8] = f2bf_(yn);
            }
        }
        gsync16(barg);

        // ---------- stage 3 ----------
        {
            floatx4 ag = {0.f, 0.f, 0.f, 0.f};
            floatx4 ad = {0.f, 0.f, 0.f, 0.f};
            floatx4 at = {0.f, 0.f, 0.f, 0.f};
            gemm3(wg, wd, wt, Ayb, m_tile, lane, ag, ad, at);
            #pragma unroll
            for (int i = 0; i < 4; ++i) {
                float gate = ag[i] + baseg[i];
                float dyn = ad[i] + based[i];
                float tau = sp_(at[i] + btau);
                float ki = (sigm_(gate) * tanhf(dyn) - ycur[i]) / (tau + lk);
                rk3[i] = ki;
                float yn = hreg[i] + dt4[i] * (rk1[i] - rk2[i] + ki);
                ycur[i] = yn;
                p.yapack[pbase + (lane_p + (quad * 4 + i)) * 8] = f2bf_(yn);
            }
        }
        gsync16(barg);

        // ---------- stage 4 ----------
        {
            floatx4 ag = {0.f, 0.f, 0.f, 0.f};
            floatx4 ad = {0.f, 0.f, 0.f, 0.f};
            floatx4 at = {0.f, 0.f, 0.f, 0.f};
            gemm3(wg, wd, wt, Aya, m_tile, lane, ag, ad, at);
            #pragma unroll
            for (int i = 0; i < 4; ++i) {
                float gate = ag[i] + baseg[i];
                float dyn = ad[i] + based[i];
                float tau = sp_(at[i] + btau);
                float ki = (sigm_(gate) * tanhf(dyn) - ycur[i]) / (tau + lk);
                hreg[i] = hreg[i] +
                          dt4[i] * (rk1[i] + 3.f * rk2[i] + 3.f * rk3[i] + ki) * 0.125f;
                p.hpack[pbase + (lane_p + (quad * 4 + i)) * 8] = f2bf_(hreg[i]);
            }
        }
        gsync16(barg);

        // ---------- phase F: K/V projection of h_next ----------
        if (w_local < 16) {
            floatx4 acc = {0.f, 0.f, 0.f, 0.f};
            #pragma unroll
            for (int kb = 0; kb < 16; ++kb) {
                short8 a = Ahp[(m_tile * 16 + kb) * 64 + lane];
                acc = __builtin_amdgcn_mfma_f32_16x16x32_bf16(
                    a, Wkv8[(c4 * 16 + kb) * 64 + lane], acc, 0, 0, 0);
            }
            #pragma unroll
            for (int i = 0; i < 4; ++i) {
                int b = m_tile * 16 + quad * 4 + i;
                kv_dst[(size_t)(b * T_ + t) * A_ + a_col] = acc[i] + kv_bias;
            }
        }
        gsync16(barg);
    }

    // ---------- write final h, then fc ----------
    #pragma unroll
    for (int i = 0; i < 4; ++i)
        p.h[(m_tile * 16 + quad * 4 + i) * H_ + c] = hreg[i];
    gsync16(barg);
    {
        const int o = tid & 31, ks = tid >> 5;
        float acc = 0.f;
        #pragma unroll 4
        for (int k = ks * 128; k < ks * 128 + 128; ++k)
            acc += p.h[r * H_ + k] * p.W_fc[k * O_ + o];
        sc[tid] = acc;
        __syncthreads();
        if (tid < 32) {
            float s = sc[tid] + sc[tid + 32] + sc[tid + 64] + sc[tid + 96] +
                      p.b_fc[tid];
            p.out[r * O_ + tid] = s;
        }
    }
}

extern "C" void kernel_launch(void* const* d_in, const int* in_sizes, int n_in,
                              void* d_out, int out_size, void* d_ws,
                              size_t ws_size, hipStream_t stream) {
    (void)in_sizes; (void)n_in; (void)out_size; (void)ws_size;
    P p;
    p.x = (const float*)d_in[0];
    p.dts = (const float*)d_in[1];
    p.Wq = (const float*)d_in[2];
    p.bq = (const float*)d_in[3];
    const float* Wk = (const float*)d_in[4];
    p.bk = (const float*)d_in[5];
    const float* Wv = (const float*)d_in[6];
    p.bv = (const float*)d_in[7];
    const float* W_gd = (const float*)d_in[8];
    p.b_gd = (const float*)d_in[9];
    const float* W_tau = (const float*)d_in[10];
    p.b_tau = (const float*)d_in[11];
    p.gleak = (const float*)d_in[12];
    p.cm = (const float*)d_in[13];
    p.W_fc = (const float*)d_in[14];
    p.b_fc = (const float*)d_in[15];
    p.out = (float*)d_out;

    float* ws = (float*)d_ws;
    p.h = ws;                            // B*H
    p.ctx = p.h + B_ * H_;               // B*A
    p.Khist = p.ctx + B_ * A_;           // B*T*A
    p.Vhist = p.Khist + (size_t)B_ * T_ * A_;
    unsigned short* Wpack = (unsigned short*)(p.Vhist + (size_t)B_ * T_ * A_);
    p.Wy = Wpack;                        // 786432 ushorts
    p.Wx = Wpack + 786432;               // 65536
    p.Wc = Wpack + 851968;               // 131072
    p.Wkv = Wpack + 983040;              // 131072
    p.hpack = Wpack + 1114112;           // B*H
    p.yapack = p.hpack + B_ * H_;
    p.ybpack = p.yapack + B_ * H_;
    p.bar = (unsigned*)(p.ybpack + B_ * H_);  // 512 uints (16 groups x 32)

    init_kernel<<<512, 256, 0, stream>>>(p.hpack, p.bar);
    pack_w_kernel<<<4352, 256, 0, stream>>>(W_gd, W_tau, Wk, Wv, Wpack);

    // Plain launch: 256 blocks x 128 threads; capacity >= 2 blocks/CU even at
    // max VGPR usage, so all blocks are co-resident and the group barrier is safe.
    fused_kernel<<<dim3(256), dim3(128), 0, stream>>>(p);
}